// Round 1
// 79.544 us; speedup vs baseline: 1.0362x; 1.0362x over previous
//
#include <hip/hip_runtime.h>

#define NJ 24
#define EPSF 1e-6f
#define PPT 2            // points per thread
#define TPB 256          // threads per block

__global__ __launch_bounds__(TPB) void shCaster_kernel(
    const float* __restrict__ xyz,          // [N,3] fp32
    const float* __restrict__ vdirs,        // [N,3] fp32
    const float* __restrict__ transforms,   // [NJ,4,4] fp32 (uniform -> s_load)
    const float* __restrict__ sh_feats,     // [NJ,9] fp32   (uniform -> s_load)
    const float* __restrict__ locs,         // [NJ,3] fp32   (uniform -> s_load)
    float* __restrict__ out,                // fp32: [3N xyz_out][3N vd_out]
    int N)
{
    constexpr float SH_C0 = 0.28209479177387814f;
    constexpr float SH_C1 = 0.4886025119029199f;
    constexpr float C2_0  = 1.0925484305920792f;   // xy / -yz / -xz coeff magnitude
    constexpr float C2_2  = 0.31539156525252005f;
    constexpr float C2_4  = 0.5462742152960396f;

    const int tid  = threadIdx.x;
    const int base = blockIdx.x * (TPB * PPT) + tid;

    int   idx[PPT];
    bool  act[PPT];
    float X[PPT][3], V[PPT][3], A[PPT][12], wsum[PPT];

#pragma unroll
    for (int p = 0; p < PPT; ++p) {
        const int n = base + p * TPB;
        act[p] = (n < N);
        const int m = act[p] ? n : 0;
        idx[p] = m;
        X[p][0] = xyz[3 * m + 0];
        X[p][1] = xyz[3 * m + 1];
        X[p][2] = xyz[3 * m + 2];
        V[p][0] = vdirs[3 * m + 0];
        V[p][1] = vdirs[3 * m + 1];
        V[p][2] = vdirs[3 * m + 2];
        wsum[p] = 0.0f;
#pragma unroll
        for (int k = 0; k < 12; ++k) A[p][k] = 0.0f;
    }

    // Joint loop: all joint data is wave-uniform -> scalar loads (s_load),
    // no LDS, no __syncthreads. Per-joint SH constants folded once, shared
    // across the PPT points.
#pragma unroll 8
    for (int j = 0; j < NJ; ++j) {
        const float4 T0 = *reinterpret_cast<const float4*>(transforms + j * 16 + 0);
        const float4 T1 = *reinterpret_cast<const float4*>(transforms + j * 16 + 4);
        const float4 T2 = *reinterpret_cast<const float4*>(transforms + j * 16 + 8);

        const float* Fj = sh_feats + j * 9;
        const float G0 =  SH_C0 * Fj[0];
        const float G1 = -SH_C1 * Fj[1];   // * dy
        const float G2 =  SH_C1 * Fj[2];   // * dz
        const float G3 = -SH_C1 * Fj[3];   // * dx
        const float G4 =  C2_0  * Fj[4];   // * dx*dy
        const float G5 = -C2_0  * Fj[5];   // * dy*dz
        const float G6 =  C2_2  * Fj[6];   // * (2zz - xx - yy)
        const float G7 = -C2_0  * Fj[7];   // * dx*dz
        const float G8 =  C2_4  * Fj[8];   // * (xx - yy)

        const float L0 = locs[j * 3 + 0];
        const float L1 = locs[j * 3 + 1];
        const float L2 = locs[j * 3 + 2];

#pragma unroll
        for (int p = 0; p < PPT; ++p) {
            const float px = fmaf(T0.x, X[p][0], fmaf(T0.y, X[p][1], fmaf(T0.z, X[p][2], T0.w)));
            const float py = fmaf(T1.x, X[p][0], fmaf(T1.y, X[p][1], fmaf(T1.z, X[p][2], T1.w)));
            const float pz = fmaf(T2.x, X[p][0], fmaf(T2.y, X[p][1], fmaf(T2.z, X[p][2], T2.w)));

            const float d0 = L0 - px, d1 = L1 - py, d2 = L2 - pz;
            const float len2 = fmaf(d0, d0, fmaf(d1, d1, d2 * d2));
            const float rlen = rsqrtf(fmaxf(len2, 1e-30f));   // NaN insurance for len2==0
            const float len  = len2 * rlen;                   // sqrt via rsqrt
            const float dx = d0 * rlen, dy = d1 * rlen, dz = d2 * rlen;

            const float xx = dx * dx, yy = dy * dy, zz = dz * dz;
            float dot = fmaf(G1, dy, G0);
            dot = fmaf(G2, dz, dot);
            dot = fmaf(G3, dx, dot);
            dot = fmaf(G4, dx * dy, dot);
            dot = fmaf(G5, dy * dz, dot);
            dot = fmaf(G7, dx * dz, dot);
            dot = fmaf(G6, fmaf(2.0f, zz, -(xx + yy)), dot);
            dot = fmaf(G8, xx - yy, dot);

            const float rads = fmaxf(dot + 0.5f, 0.0f);
            float rel = fmaxf(1.0f - __fdividef(len, fmaxf(rads, EPSF)), 0.0f);
            rel = (rads < EPSF) ? 0.0f : rel;

            wsum[p] += rel;
            A[p][0]  = fmaf(rel, T0.x, A[p][0]);
            A[p][1]  = fmaf(rel, T0.y, A[p][1]);
            A[p][2]  = fmaf(rel, T0.z, A[p][2]);
            A[p][3]  = fmaf(rel, T0.w, A[p][3]);
            A[p][4]  = fmaf(rel, T1.x, A[p][4]);
            A[p][5]  = fmaf(rel, T1.y, A[p][5]);
            A[p][6]  = fmaf(rel, T1.z, A[p][6]);
            A[p][7]  = fmaf(rel, T1.w, A[p][7]);
            A[p][8]  = fmaf(rel, T2.x, A[p][8]);
            A[p][9]  = fmaf(rel, T2.y, A[p][9]);
            A[p][10] = fmaf(rel, T2.z, A[p][10]);
            A[p][11] = fmaf(rel, T2.w, A[p][11]);
        }
    }

#pragma unroll
    for (int p = 0; p < PPT; ++p) {
        if (!act[p]) continue;
        const int n = idx[p];
        const float inv = __fdividef(1.0f, fmaxf(wsum[p], EPSF));

        const float bx0 = fmaf(A[p][0], X[p][0], fmaf(A[p][1], X[p][1], fmaf(A[p][2],  X[p][2], A[p][3])))  * inv;
        const float bx1 = fmaf(A[p][4], X[p][0], fmaf(A[p][5], X[p][1], fmaf(A[p][6],  X[p][2], A[p][7])))  * inv;
        const float bx2 = fmaf(A[p][8], X[p][0], fmaf(A[p][9], X[p][1], fmaf(A[p][10], X[p][2], A[p][11]))) * inv;
        // translation cancels in xyz - (xyz - viewdirs): rotation-only on v
        const float bv0 = fmaf(A[p][0], V[p][0], fmaf(A[p][1], V[p][1], A[p][2]  * V[p][2])) * inv;
        const float bv1 = fmaf(A[p][4], V[p][0], fmaf(A[p][5], V[p][1], A[p][6]  * V[p][2])) * inv;
        const float bv2 = fmaf(A[p][8], V[p][0], fmaf(A[p][9], V[p][1], A[p][10] * V[p][2])) * inv;

        const bool valid = wsum[p] > EPSF;
        out[3 * n + 0] = valid ? bx0 : X[p][0];
        out[3 * n + 1] = valid ? bx1 : X[p][1];
        out[3 * n + 2] = valid ? bx2 : X[p][2];
        float* outv = out + 3LL * N;
        outv[3 * n + 0] = valid ? bv0 : V[p][0];
        outv[3 * n + 1] = valid ? bv1 : V[p][1];
        outv[3 * n + 2] = valid ? bv2 : V[p][2];
    }
}

extern "C" void kernel_launch(void* const* d_in, const int* in_sizes, int n_in,
                              void* d_out, int out_size, void* d_ws, size_t ws_size,
                              hipStream_t stream) {
    const float* xyz        = (const float*)d_in[0];
    const float* vdirs      = (const float*)d_in[1];
    const float* transforms = (const float*)d_in[2];
    const float* sh_feats   = (const float*)d_in[3];
    const float* locs       = (const float*)d_in[4];
    float* out = (float*)d_out;

    const int N = in_sizes[0] / 3;   // 2048*128 = 262144 points
    if (N <= 0) return;
    const int pts_per_block = TPB * PPT;
    const int blocks = (N + pts_per_block - 1) / pts_per_block;
    shCaster_kernel<<<blocks, TPB, 0, stream>>>(
        xyz, vdirs, transforms, sh_feats, locs, out, N);
}